// Round 23
// baseline (169.155 us; speedup 1.0000x reference)
//
#include <hip/hip_runtime.h>
#include <hip/hip_fp16.h>

#define I_DIM 2304
#define J_DIM 32
#define D_IN  8
#define E_DIM 16
#define B_DIM 64
#define BJE   (B_DIM * J_DIM * E_DIM)  // 32768
#define HBJE  (BJE / 2)                // 16384 half2 per chunk slice
#define NC7   256
#define CH7   (I_DIM / NC7)            // 9
#define TILEW 4096                     // floats per 16KB W tile

typedef const __attribute__((address_space(1))) char* gcp_t;
typedef __attribute__((address_space(3)))       char* lcp_t;

// s += permuted(s) via DPP (VALU pipe, not LDS). ctrl must be a literal.
#define DPP_ADD(s, ctrl) ((s) + __int_as_float(__builtin_amdgcn_update_dpp( \
    0, __float_as_int(s), (ctrl), 0xF, 0xF, true)))

// v23: u_hat is pass-invariant -> compute it ONCE (pass 0) and cache as f16
// in ws (151 MB; ws = 256 MiB measured via harness poison fill). Passes 1-2
// become pure streaming kernels (no W DMA, no LDS, no barriers) — deleting
// the phase-locked iteration structure that resisted 5 scheduling attacks
// (r12-r21). u_hat unit layout (16B per lane): unit = i*4096 + qb*1024 +
// wv*256 + bb*64 + lane -> 1KB contiguous per (bb) wave store/load.
// Pass 0 = v22's FIRST path + u_hat stores (issued early; drain soaked by
// the measured 40% idle). f16 u_hat err ~5e-4 rel -> absmax ~<6e-3 vs 1.6e-2.

// ---------------- pass 0: compute u_hat, store f16; partial from c=softmax(b0)
__global__ __launch_bounds__(256, 2) void caps_pass0(
    const float* __restrict__ x,      // [B, I, 8]
    const float* __restrict__ W,      // [I, J, 8, 16]
    const float* __restrict__ b0,     // [I, J]
    __half2* __restrict__ partial,    // [NC7][HBJE]
    int4* __restrict__ uh_buf)        // u_hat f16, 16B units
{
    const int tid   = threadIdx.x;
    const int wv    = __builtin_amdgcn_readfirstlane(tid >> 6);  // SGPR (staging)
    const int wvx   = tid >> 6;
    const int lane  = tid & 63;
    const int jj    = lane & 31;
    const int eh    = lane >> 5;
    const int km    = jj & 15;
    const int chunk = blockIdx.x & (NC7 - 1);
    const int qb    = blockIdx.x >> 8;
    const int i0    = chunk * CH7;
    const int bloc0 = wv * 4;
    const int bbase = qb * 16 + bloc0;
    const int bxb   = qb * 16 + wvx * 4;

    __shared__ float Ws[2][TILEW];      // exactly 32 KB

    auto stage = [&](int buf, int itile) {
        const char* wt = (const char*)(W + (size_t)itile * TILEW);
#pragma unroll
        for (int r = 0; r < 4; ++r) {
            const int g    = (wv * 4 + r) * 64 + lane;
            const int srcu = (g & ~31) | ((g & 31) ^ ((g >> 5) & 15));
            __builtin_amdgcn_global_load_lds(
                (gcp_t)(wt + (size_t)srcu * 16),
                (lcp_t)((char*)&Ws[buf][(wv * 4 + r) * 256]),
                16, 0, 0);
        }
    };

    stage(0, i0);

    float Sacc[4][8];
#pragma unroll
    for (int bb = 0; bb < 4; ++bb)
#pragma unroll
        for (int e = 0; e < 8; ++e) Sacc[bb][e] = 0.f;

    __syncthreads();

    int cur = 0;
    for (int ii = 0; ii < CH7; ++ii) {
        const int i = i0 + ii;
        if (ii + 1 < CH7) stage(cur ^ 1, i + 1);

        const float b0v = b0[i * J_DIM + jj];
        const float* wb = &Ws[cur][0];

        float uh[4][8];
#pragma unroll
        for (int bb = 0; bb < 4; ++bb)
#pragma unroll
            for (int e = 0; e < 8; ++e) uh[bb][e] = 0.f;

        // ---- group A: d = 0..3 ----
        {
            float xq[4][4];
#pragma unroll
            for (int bb = 0; bb < 4; ++bb) {
                const float4 t = *(const float4*)(x + ((size_t)(bxb + bb) * I_DIM + i) * D_IN);
                xq[bb][0]=t.x; xq[bb][1]=t.y; xq[bb][2]=t.z; xq[bb][3]=t.w;
            }
            float4 w[8];
#pragma unroll
            for (int d = 0; d < 4; ++d) {
                const int u0 = (d << 2) | (eh << 1);
                w[2*d]   = *(const float4*)&wb[jj * 128 + (((u0    ) ^ km) << 2)];
                w[2*d+1] = *(const float4*)&wb[jj * 128 + (((u0 | 1) ^ km) << 2)];
            }
#pragma unroll
            for (int d = 0; d < 4; ++d) {
                const float4 wlo = w[2*d], whi = w[2*d+1];
#pragma unroll
                for (int bb = 0; bb < 4; ++bb) {
                    const float xv = xq[bb][d];
                    uh[bb][0] = fmaf(xv, wlo.x, uh[bb][0]);
                    uh[bb][1] = fmaf(xv, wlo.y, uh[bb][1]);
                    uh[bb][2] = fmaf(xv, wlo.z, uh[bb][2]);
                    uh[bb][3] = fmaf(xv, wlo.w, uh[bb][3]);
                    uh[bb][4] = fmaf(xv, whi.x, uh[bb][4]);
                    uh[bb][5] = fmaf(xv, whi.y, uh[bb][5]);
                    uh[bb][6] = fmaf(xv, whi.z, uh[bb][6]);
                    uh[bb][7] = fmaf(xv, whi.w, uh[bb][7]);
                }
            }
        }
        // ---- group B: d = 4..7 ----
        {
            float xq[4][4];
#pragma unroll
            for (int bb = 0; bb < 4; ++bb) {
                const float4 t = *(const float4*)(x + ((size_t)(bxb + bb) * I_DIM + i) * D_IN + 4);
                xq[bb][0]=t.x; xq[bb][1]=t.y; xq[bb][2]=t.z; xq[bb][3]=t.w;
            }
            float4 w[8];
#pragma unroll
            for (int d = 4; d < 8; ++d) {
                const int u0 = (d << 2) | (eh << 1);
                w[2*(d-4)]   = *(const float4*)&wb[jj * 128 + (((u0    ) ^ km) << 2)];
                w[2*(d-4)+1] = *(const float4*)&wb[jj * 128 + (((u0 | 1) ^ km) << 2)];
            }
#pragma unroll
            for (int d = 0; d < 4; ++d) {
                const float4 wlo = w[2*d], whi = w[2*d+1];
#pragma unroll
                for (int bb = 0; bb < 4; ++bb) {
                    const float xv = xq[bb][d];
                    uh[bb][0] = fmaf(xv, wlo.x, uh[bb][0]);
                    uh[bb][1] = fmaf(xv, wlo.y, uh[bb][1]);
                    uh[bb][2] = fmaf(xv, wlo.z, uh[bb][2]);
                    uh[bb][3] = fmaf(xv, wlo.w, uh[bb][3]);
                    uh[bb][4] = fmaf(xv, whi.x, uh[bb][4]);
                    uh[bb][5] = fmaf(xv, whi.y, uh[bb][5]);
                    uh[bb][6] = fmaf(xv, whi.z, uh[bb][6]);
                    uh[bb][7] = fmaf(xv, whi.w, uh[bb][7]);
                }
            }
        }

        // ---- store u_hat f16 (early: drain latency soaked by softmax below) ----
        {
            int4* ub = uh_buf + (size_t)i * 4096 + qb * 1024 + wv * 256 + lane;
#pragma unroll
            for (int bb = 0; bb < 4; ++bb) {
                __half2 h0 = __floats2half2_rn(uh[bb][0], uh[bb][1]);
                __half2 h1 = __floats2half2_rn(uh[bb][2], uh[bb][3]);
                __half2 h2 = __floats2half2_rn(uh[bb][4], uh[bb][5]);
                __half2 h3 = __floats2half2_rn(uh[bb][6], uh[bb][7]);
                ub[bb * 64] = make_int4(*(int*)&h0, *(int*)&h1, *(int*)&h2, *(int*)&h3);
            }
        }

        // ---- softmax (pass 0: logit = b0 only) + Sacc ----
        {
            const float p = __expf(b0v);
            float s = p;
            s = DPP_ADD(s, 0xB1);
            s = DPP_ADD(s, 0x4E);
            s = DPP_ADD(s, 0x124);
            s = DPP_ADD(s, 0x128);
            s += __shfl_xor(s, 16);
            const float c = p * __builtin_amdgcn_rcpf(s);
#pragma unroll
            for (int bb = 0; bb < 4; ++bb)
#pragma unroll
                for (int e = 0; e < 8; ++e) Sacc[bb][e] = fmaf(c, uh[bb][e], Sacc[bb][e]);
        }

        __syncthreads();
        cur ^= 1;
    }

#pragma unroll
    for (int bb = 0; bb < 4; ++bb) {
        __half2 h0 = __floats2half2_rn(Sacc[bb][0], Sacc[bb][1]);
        __half2 h1 = __floats2half2_rn(Sacc[bb][2], Sacc[bb][3]);
        __half2 h2 = __floats2half2_rn(Sacc[bb][4], Sacc[bb][5]);
        __half2 h3 = __floats2half2_rn(Sacc[bb][6], Sacc[bb][7]);
        __half2* pp = partial + (size_t)chunk * HBJE
                    + ((size_t)((bbase + bb) * J_DIM + jj)) * (E_DIM / 2) + eh * 4;
        *(int4*)pp = make_int4(*(int*)&h0, *(int*)&h1, *(int*)&h2, *(int*)&h3);
    }
}

// ---------------- passes 1-2: stream cached u_hat; no LDS, no barriers ----
__global__ __launch_bounds__(256, 2) void caps_pass_uh(
    const int4* __restrict__ uh_buf,  // u_hat f16, 16B units
    const float* __restrict__ b0,     // [I, J]
    const float* __restrict__ Vacc,   // [B, J, 16] fp32
    __half2* __restrict__ partial)    // [NC7][HBJE]
{
    const int tid   = threadIdx.x;
    const int wvx   = tid >> 6;
    const int lane  = tid & 63;
    const int jj    = lane & 31;
    const int eh    = lane >> 5;
    const int chunk = blockIdx.x & (NC7 - 1);
    const int qb    = blockIdx.x >> 8;
    const int i0    = chunk * CH7;
    const int bbase = qb * 16 + wvx * 4;

    float vacc[4][8];
#pragma unroll
    for (int bb = 0; bb < 4; ++bb) {
        const float* vp = Vacc + ((size_t)((bbase + bb) * J_DIM + jj)) * E_DIM + eh * 8;
        const float4 v0 = *(const float4*)vp;
        const float4 v1 = *(const float4*)(vp + 4);
        vacc[bb][0]=v0.x; vacc[bb][1]=v0.y; vacc[bb][2]=v0.z; vacc[bb][3]=v0.w;
        vacc[bb][4]=v1.x; vacc[bb][5]=v1.y; vacc[bb][6]=v1.z; vacc[bb][7]=v1.w;
    }

    float Sacc[4][8];
#pragma unroll
    for (int bb = 0; bb < 4; ++bb)
#pragma unroll
        for (int e = 0; e < 8; ++e) Sacc[bb][e] = 0.f;

#pragma unroll
    for (int ii = 0; ii < CH7; ++ii) {
        const int i = i0 + ii;
        const float b0v = b0[i * J_DIM + jj];

        // batched independent u_hat loads (software-pipelined by compiler;
        // no barriers in this kernel, 16 waves/CU hide the rest)
        const int4* ub = uh_buf + (size_t)i * 4096 + qb * 1024 + wvx * 256 + lane;
        int4 u[4];
#pragma unroll
        for (int bb = 0; bb < 4; ++bb) u[bb] = ub[bb * 64];

#pragma unroll
        for (int bb = 0; bb < 4; ++bb) {
            const float2 f0 = __half22float2(*(const __half2*)&u[bb].x);
            const float2 f1 = __half22float2(*(const __half2*)&u[bb].y);
            const float2 f2 = __half22float2(*(const __half2*)&u[bb].z);
            const float2 f3 = __half22float2(*(const __half2*)&u[bb].w);
            const float uhf[8] = {f0.x, f0.y, f1.x, f1.y, f2.x, f2.y, f3.x, f3.y};

            float l0 = 0.f, l1 = 0.f;
#pragma unroll
            for (int e = 0; e < 8; e += 2) {
                l0 = fmaf(vacc[bb][e],     uhf[e],     l0);
                l1 = fmaf(vacc[bb][e + 1], uhf[e + 1], l1);
            }
            float lg = l0 + l1;
            lg += __shfl_xor(lg, 32);          // other e-half
            const float l = b0v + lg;

            const float p = __expf(l);
            float s = p;
            s = DPP_ADD(s, 0xB1);
            s = DPP_ADD(s, 0x4E);
            s = DPP_ADD(s, 0x124);
            s = DPP_ADD(s, 0x128);
            s += __shfl_xor(s, 16);
            const float c = p * __builtin_amdgcn_rcpf(s);

#pragma unroll
            for (int e = 0; e < 8; ++e) Sacc[bb][e] = fmaf(c, uhf[e], Sacc[bb][e]);
        }
    }

#pragma unroll
    for (int bb = 0; bb < 4; ++bb) {
        __half2 h0 = __floats2half2_rn(Sacc[bb][0], Sacc[bb][1]);
        __half2 h1 = __floats2half2_rn(Sacc[bb][2], Sacc[bb][3]);
        __half2 h2 = __floats2half2_rn(Sacc[bb][4], Sacc[bb][5]);
        __half2 h3 = __floats2half2_rn(Sacc[bb][6], Sacc[bb][7]);
        __half2* pp = partial + (size_t)chunk * HBJE
                    + ((size_t)((bbase + bb) * J_DIM + jj)) * (E_DIM / 2) + eh * 4;
        *(int4*)pp = make_int4(*(int*)&h0, *(int*)&h1, *(int*)&h2, *(int*)&h3);
    }
}

// Sum f16 partials over chunks, squash. t indexes an e-PAIR.
__global__ __launch_bounds__(256) void reduce_squash(
    const __half2* __restrict__ partial, float* __restrict__ Vacc,
    float* __restrict__ out, const int nc, const int first_it, const int final_it)
{
    const int t = blockIdx.x * blockDim.x + threadIdx.x;  // 0..HBJE-1
    float ax0=0.f,ay0=0.f,ax1=0.f,ay1=0.f,ax2=0.f,ay2=0.f,ax3=0.f,ay3=0.f;
    for (int c = 0; c < nc; c += 4) {
        const float2 f0 = __half22float2(partial[(size_t)(c+0) * HBJE + t]);
        const float2 f1 = __half22float2(partial[(size_t)(c+1) * HBJE + t]);
        const float2 f2 = __half22float2(partial[(size_t)(c+2) * HBJE + t]);
        const float2 f3 = __half22float2(partial[(size_t)(c+3) * HBJE + t]);
        ax0 += f0.x; ay0 += f0.y;
        ax1 += f1.x; ay1 += f1.y;
        ax2 += f2.x; ay2 += f2.y;
        ax3 += f3.x; ay3 += f3.y;
    }
    const float sx = (ax0 + ax1) + (ax2 + ax3);
    const float sy = (ay0 + ay1) + (ay2 + ay3);

    float s2 = sx * sx + sy * sy;
#pragma unroll
    for (int k = 4; k >= 1; k >>= 1) s2 += __shfl_xor(s2, k);
    const float scale = s2 / (1.f + s2) * rsqrtf(s2 + 1e-7f);
    const float2 v = make_float2(scale * sx, scale * sy);
    if (final_it)      *(float2*)(out  + 2 * (size_t)t) = v;
    else if (first_it) *(float2*)(Vacc + 2 * (size_t)t) = v;
    else {
        float2 old = *(const float2*)(Vacc + 2 * (size_t)t);
        *(float2*)(Vacc + 2 * (size_t)t) = make_float2(old.x + v.x, old.y + v.y);
    }
}

extern "C" void kernel_launch(void* const* d_in, const int* in_sizes, int n_in,
                              void* d_out, int out_size, void* d_ws, size_t ws_size,
                              hipStream_t stream) {
    const float* x  = (const float*)d_in[0];   // [64,2304,8]
    const float* W  = (const float*)d_in[1];   // [2304,32,8,16]
    const float* b0 = (const float*)d_in[2];   // [2304,32]
    float* out = (float*)d_out;                // [64,32,16]

    // ws layout: partial[256][HBJE] half2 (16.8 MB) + Vacc[BJE] f32 (128 KB)
    // + uh_buf f16 (151 MB) = ~168 MB < 256 MiB (measured). All state is
    // written before read within each call -> harness poison-safe.
    __half2* partial = (__half2*)d_ws;
    float*   Vacc    = (float*)(partial + (size_t)NC7 * HBJE);
    int4*    uh_buf  = (int4*)(Vacc + BJE);

    caps_pass0<<<NC7 * 4, 256, 0, stream>>>(x, W, b0, partial, uh_buf);
    reduce_squash<<<HBJE / 256, 256, 0, stream>>>(partial, Vacc, out, NC7, 1, 0);

    caps_pass_uh<<<NC7 * 4, 256, 0, stream>>>(uh_buf, b0, Vacc, partial);
    reduce_squash<<<HBJE / 256, 256, 0, stream>>>(partial, Vacc, out, NC7, 0, 0);

    caps_pass_uh<<<NC7 * 4, 256, 0, stream>>>(uh_buf, b0, Vacc, partial);
    reduce_squash<<<HBJE / 256, 256, 0, stream>>>(partial, Vacc, out, NC7, 0, 1);
}

// Round 24
// 162.376 us; speedup vs baseline: 1.0417x; 1.0417x over previous
//
#include <hip/hip_runtime.h>
#include <hip/hip_fp16.h>

#define I_DIM 2304
#define J_DIM 32
#define D_IN  8
#define E_DIM 16
#define B_DIM 64
#define BJE   (B_DIM * J_DIM * E_DIM)  // 32768
#define HBJE  (BJE / 2)                // 16384 half2 per chunk slice
#define NC7   256
#define CH7   (I_DIM / NC7)            // 9
#define TILEW 4096                     // floats per 16KB W tile

typedef const __attribute__((address_space(1))) char* gcp_t;
typedef __attribute__((address_space(3)))       char* lcp_t;

// s += permuted(s) via DPP (VALU pipe, not LDS). ctrl must be a literal.
#define DPP_ADD(s, ctrl) ((s) + __int_as_float(__builtin_amdgcn_update_dpp( \
    0, __float_as_int(s), (ctrl), 0xF, 0xF, true)))

// FINAL (v24 = v22 = v20): best-measured configuration, 162.5us total.
// r23's u_hat-cache experiment regressed (169us: store+reload 302MB cost more
// than the deleted recompute) -> reverted per pre-registration.
// Configuration (levers measured r12-r23):
//  - 256 chunks x 4 b-quarters, 256 thr, (256,2): VGPR 68, zero spill
//  - W staged via source-XOR-swizzled global_load_lds, double-buffered,
//    one barrier/iter (counted-vmcnt pipeline was SLOWER, r15)
//  - x via uniform VMEM float4 (L1 broadcast), b0 coalesced global
//  - DPP softmax (within-16 on VALU), f16-packed partials (16.8MB)
//  - FIRST template: pass 0 never reads Vacc (harness poison-safe, r11)
template <bool FIRST>
__global__ __launch_bounds__(256, 2) void caps_pass_fin(
    const float* __restrict__ x,      // [B, I, 8]
    const float* __restrict__ W,      // [I, J, 8, 16]
    const float* __restrict__ b0,     // [I, J]
    const float* __restrict__ Vacc,   // [B, J, 16] fp32 (ignored when FIRST)
    __half2* __restrict__ partial)    // [NC7][HBJE]
{
    const int tid   = threadIdx.x;
    const int wv    = __builtin_amdgcn_readfirstlane(tid >> 6);  // SGPR (staging)
    const int wvx   = tid >> 6;         // NOT readfirstlane: keeps x addr in VGPR
    const int lane  = tid & 63;
    const int jj    = lane & 31;
    const int eh    = lane >> 5;
    const int km    = jj & 15;
    const int chunk = blockIdx.x & (NC7 - 1);
    const int qb    = blockIdx.x >> 8;
    const int i0    = chunk * CH7;
    const int bloc0 = wv * 4;           // local b base (SGPR)
    const int bbase = qb * 16 + bloc0;
    const int bxb   = qb * 16 + wvx * 4; // b base for x addressing (VGPR-typed)

    __shared__ float Ws[2][TILEW];      // exactly 32 KB

    auto stage = [&](int buf, int itile) {
        const char* wt = (const char*)(W + (size_t)itile * TILEW);
#pragma unroll
        for (int r = 0; r < 4; ++r) {
            const int g    = (wv * 4 + r) * 64 + lane;                  // linear dest unit
            const int srcu = (g & ~31) | ((g & 31) ^ ((g >> 5) & 15));  // swizzled src
            __builtin_amdgcn_global_load_lds(
                (gcp_t)(wt + (size_t)srcu * 16),
                (lcp_t)((char*)&Ws[buf][(wv * 4 + r) * 256]),
                16, 0, 0);
        }
    };

    // ---- prologue staging (drained by the first barrier) ----
    stage(0, i0);

    float vacc[4][8];
    if constexpr (!FIRST) {
#pragma unroll
        for (int bb = 0; bb < 4; ++bb) {
            const float* vp = Vacc + ((size_t)((bbase + bb) * J_DIM + jj)) * E_DIM + eh * 8;
            const float4 v0 = *(const float4*)vp;
            const float4 v1 = *(const float4*)(vp + 4);
            vacc[bb][0]=v0.x; vacc[bb][1]=v0.y; vacc[bb][2]=v0.z; vacc[bb][3]=v0.w;
            vacc[bb][4]=v1.x; vacc[bb][5]=v1.y; vacc[bb][6]=v1.z; vacc[bb][7]=v1.w;
        }
    }

    float Sacc[4][8];
#pragma unroll
    for (int bb = 0; bb < 4; ++bb)
#pragma unroll
        for (int e = 0; e < 8; ++e) Sacc[bb][e] = 0.f;

    __syncthreads();   // tile 0 visible

    int cur = 0;
    for (int ii = 0; ii < CH7; ++ii) {
        const int i = i0 + ii;
        if (ii + 1 < CH7) stage(cur ^ 1, i + 1);   // DMA hides under compute

        // b0: coalesced 128B/wave global load (L2-hot), latency hidden below.
        const float b0v = b0[i * J_DIM + jj];

        const float* wb = &Ws[cur][0];

        float uh[4][8];
#pragma unroll
        for (int bb = 0; bb < 4; ++bb)
#pragma unroll
            for (int e = 0; e < 8; ++e) uh[bb][e] = 0.f;

        // ================= group A: d = 0..3 =================
        {
            float xq[4][4];
#pragma unroll
            for (int bb = 0; bb < 4; ++bb) {   // uniform VMEM loads (L1 broadcast)
                const float4 t = *(const float4*)(x + ((size_t)(bxb + bb) * I_DIM + i) * D_IN);
                xq[bb][0]=t.x; xq[bb][1]=t.y; xq[bb][2]=t.z; xq[bb][3]=t.w;
            }
            float4 w[8];
#pragma unroll
            for (int d = 0; d < 4; ++d) {
                const int u0 = (d << 2) | (eh << 1);
                w[2*d]   = *(const float4*)&wb[jj * 128 + (((u0    ) ^ km) << 2)];
                w[2*d+1] = *(const float4*)&wb[jj * 128 + (((u0 | 1) ^ km) << 2)];
            }
#pragma unroll
            for (int d = 0; d < 4; ++d) {
                const float4 wlo = w[2*d], whi = w[2*d+1];
#pragma unroll
                for (int bb = 0; bb < 4; ++bb) {
                    const float xv = xq[bb][d];
                    uh[bb][0] = fmaf(xv, wlo.x, uh[bb][0]);
                    uh[bb][1] = fmaf(xv, wlo.y, uh[bb][1]);
                    uh[bb][2] = fmaf(xv, wlo.z, uh[bb][2]);
                    uh[bb][3] = fmaf(xv, wlo.w, uh[bb][3]);
                    uh[bb][4] = fmaf(xv, whi.x, uh[bb][4]);
                    uh[bb][5] = fmaf(xv, whi.y, uh[bb][5]);
                    uh[bb][6] = fmaf(xv, whi.z, uh[bb][6]);
                    uh[bb][7] = fmaf(xv, whi.w, uh[bb][7]);
                }
            }
        }
        // ================= group B: d = 4..7 =================
        {
            float xq[4][4];
#pragma unroll
            for (int bb = 0; bb < 4; ++bb) {
                const float4 t = *(const float4*)(x + ((size_t)(bxb + bb) * I_DIM + i) * D_IN + 4);
                xq[bb][0]=t.x; xq[bb][1]=t.y; xq[bb][2]=t.z; xq[bb][3]=t.w;
            }
            float4 w[8];
#pragma unroll
            for (int d = 4; d < 8; ++d) {
                const int u0 = (d << 2) | (eh << 1);
                w[2*(d-4)]   = *(const float4*)&wb[jj * 128 + (((u0    ) ^ km) << 2)];
                w[2*(d-4)+1] = *(const float4*)&wb[jj * 128 + (((u0 | 1) ^ km) << 2)];
            }
#pragma unroll
            for (int d = 0; d < 4; ++d) {
                const float4 wlo = w[2*d], whi = w[2*d+1];
#pragma unroll
                for (int bb = 0; bb < 4; ++bb) {
                    const float xv = xq[bb][d];
                    uh[bb][0] = fmaf(xv, wlo.x, uh[bb][0]);
                    uh[bb][1] = fmaf(xv, wlo.y, uh[bb][1]);
                    uh[bb][2] = fmaf(xv, wlo.z, uh[bb][2]);
                    uh[bb][3] = fmaf(xv, wlo.w, uh[bb][3]);
                    uh[bb][4] = fmaf(xv, whi.x, uh[bb][4]);
                    uh[bb][5] = fmaf(xv, whi.y, uh[bb][5]);
                    uh[bb][6] = fmaf(xv, whi.z, uh[bb][6]);
                    uh[bb][7] = fmaf(xv, whi.w, uh[bb][7]);
                }
            }
        }

#pragma unroll
        for (int bb = 0; bb < 4; ++bb) {
            float l;
            if constexpr (FIRST) {
                l = b0v;                           // vacc == 0 on pass 0
            } else {
                float l0 = 0.f, l1 = 0.f;
#pragma unroll
                for (int e = 0; e < 8; e += 2) {
                    l0 = fmaf(vacc[bb][e],     uh[bb][e],     l0);
                    l1 = fmaf(vacc[bb][e + 1], uh[bb][e + 1], l1);
                }
                float lg = l0 + l1;
                lg += __shfl_xor(lg, 32);          // other e-half (LDS, kept)
                l = b0v + lg;
            }

            // softmax over jj: within-16 sum on the VALU (DPP), xor16 on LDS.
            const float p = __expf(l);
            float s = p;
            s = DPP_ADD(s, 0xB1);    // xor1  (quad_perm [1,0,3,2])
            s = DPP_ADD(s, 0x4E);    // xor2  (quad_perm [2,3,0,1])
            s = DPP_ADD(s, 0x124);   // ror4  within 16-row
            s = DPP_ADD(s, 0x128);   // ror8  -> row-16 sum
            s += __shfl_xor(s, 16);  // cross 16-row -> 32-lane sum
            const float c = p * __builtin_amdgcn_rcpf(s);

#pragma unroll
            for (int e = 0; e < 8; ++e) Sacc[bb][e] = fmaf(c, uh[bb][e], Sacc[bb][e]);
        }

        __syncthreads();   // drains DMA; next tile ready; readers done with cur
        cur ^= 1;
    }

    // ---- epilogue: pack 8 fp32 -> 4 half2 (16 B) per bb, vector store ----
#pragma unroll
    for (int bb = 0; bb < 4; ++bb) {
        __half2 h0 = __floats2half2_rn(Sacc[bb][0], Sacc[bb][1]);
        __half2 h1 = __floats2half2_rn(Sacc[bb][2], Sacc[bb][3]);
        __half2 h2 = __floats2half2_rn(Sacc[bb][4], Sacc[bb][5]);
        __half2 h3 = __floats2half2_rn(Sacc[bb][6], Sacc[bb][7]);
        __half2* pp = partial + (size_t)chunk * HBJE
                    + ((size_t)((bbase + bb) * J_DIM + jj)) * (E_DIM / 2) + eh * 4;
        int4 pk = make_int4(*(int*)&h0, *(int*)&h1, *(int*)&h2, *(int*)&h3);
        *(int4*)pp = pk;
    }
}

// Sum f16 partials over chunks (8 independent f32 accumulator pairs), squash.
// t indexes an e-PAIR: (b,j) = t>>3, pair = t&7 (16 e = 8 pairs).
// first_it: WRITE Vacc; final_it: write out. Both fp32.
__global__ __launch_bounds__(256) void reduce_squash(
    const __half2* __restrict__ partial, float* __restrict__ Vacc,
    float* __restrict__ out, const int nc, const int first_it, const int final_it)
{
    const int t = blockIdx.x * blockDim.x + threadIdx.x;  // 0..HBJE-1
    float ax0=0.f,ay0=0.f,ax1=0.f,ay1=0.f,ax2=0.f,ay2=0.f,ax3=0.f,ay3=0.f;
    for (int c = 0; c < nc; c += 4) {
        const float2 f0 = __half22float2(partial[(size_t)(c+0) * HBJE + t]);
        const float2 f1 = __half22float2(partial[(size_t)(c+1) * HBJE + t]);
        const float2 f2 = __half22float2(partial[(size_t)(c+2) * HBJE + t]);
        const float2 f3 = __half22float2(partial[(size_t)(c+3) * HBJE + t]);
        ax0 += f0.x; ay0 += f0.y;
        ax1 += f1.x; ay1 += f1.y;
        ax2 += f2.x; ay2 += f2.y;
        ax3 += f3.x; ay3 += f3.y;
    }
    const float sx = (ax0 + ax1) + (ax2 + ax3);
    const float sy = (ay0 + ay1) + (ay2 + ay3);

    float s2 = sx * sx + sy * sy;
#pragma unroll
    for (int k = 4; k >= 1; k >>= 1) s2 += __shfl_xor(s2, k);  // 8 pairs -> 16 e
    const float scale = s2 / (1.f + s2) * rsqrtf(s2 + 1e-7f);
    const float2 v = make_float2(scale * sx, scale * sy);
    if (final_it)      *(float2*)(out  + 2 * (size_t)t) = v;
    else if (first_it) *(float2*)(Vacc + 2 * (size_t)t) = v;
    else {
        float2 old = *(const float2*)(Vacc + 2 * (size_t)t);
        *(float2*)(Vacc + 2 * (size_t)t) = make_float2(old.x + v.x, old.y + v.y);
    }
}

extern "C" void kernel_launch(void* const* d_in, const int* in_sizes, int n_in,
                              void* d_out, int out_size, void* d_ws, size_t ws_size,
                              hipStream_t stream) {
    const float* x  = (const float*)d_in[0];   // [64,2304,8]
    const float* W  = (const float*)d_in[1];   // [2304,32,8,16]
    const float* b0 = (const float*)d_in[2];   // [2304,32]
    float* out = (float*)d_out;                // [64,32,16]

    // ws layout: partial[256][HBJE] __half2 (16.8 MB) + Vacc[BJE] f32 (128 KB).
    // Pass 0 never reads Vacc; reduce_squash writes it fresh each call ->
    // safe under harness ws poisoning.
    __half2* partial = (__half2*)d_ws;
    float*   Vacc    = (float*)(partial + (size_t)NC7 * HBJE);

    caps_pass_fin<true><<<NC7 * 4, 256, 0, stream>>>(x, W, b0, Vacc, partial);
    reduce_squash<<<HBJE / 256, 256, 0, stream>>>(partial, Vacc, out, NC7, 1, 0);

    caps_pass_fin<false><<<NC7 * 4, 256, 0, stream>>>(x, W, b0, Vacc, partial);
    reduce_squash<<<HBJE / 256, 256, 0, stream>>>(partial, Vacc, out, NC7, 0, 0);

    caps_pass_fin<false><<<NC7 * 4, 256, 0, stream>>>(x, W, b0, Vacc, partial);
    reduce_squash<<<HBJE / 256, 256, 0, stream>>>(partial, Vacc, out, NC7, 0, 1);
}